// Round 2
// baseline (1376.545 us; speedup 1.0000x reference)
//
#include <hip/hip_runtime.h>
#include <math.h>
#include <stdint.h>

#define DEV static __device__ __forceinline__
typedef unsigned short u16;

constexpr int D    = 256;
constexpr int S    = 4096;
constexpr int NB   = 4;
constexpr int QSTR = 272;   // Qb/Kb row stride: 256 data + 12 bias-ext + 4 zero

typedef short bf16x8 __attribute__((ext_vector_type(8)));
typedef float f32x16 __attribute__((ext_vector_type(16)));

DEV u16 f2bf(float f){ unsigned u = __float_as_uint(f); return (u16)((u + 0x7fffu + ((u>>16)&1u)) >> 16); }
DEV float bf2f(u16 h){ return __uint_as_float(((unsigned)h)<<16); }
DEV int swz8(int chunk, int row){ return (chunk & ~7) | ((chunk ^ row) & 7); }  // 16B-chunk XOR swizzle

// ---------------- prep: split x and W into bf16 hi/lo; write bias-ext columns ----------------
__global__ __launch_bounds__(256) void msp_prep(
    const float* __restrict__ x, const float* __restrict__ Wq,
    const float* __restrict__ Wk, const float* __restrict__ Wv,
    const float* __restrict__ beta,
    u16* __restrict__ xh, u16* __restrict__ xl,
    u16* __restrict__ Wh, u16* __restrict__ Wl,
    u16* __restrict__ Qb, u16* __restrict__ Kb)
{
  const int blk = blockIdx.x, tid = threadIdx.x;
  if (blk < 2048) {                       // x: 4x4096x256 = 2048 blocks * 2048 elts
    size_t u = (size_t)blk*2048 + tid*8;
    const float* p = x + u;
    union { u16 s[8]; uint4 v; } hh, ll;
    #pragma unroll
    for (int i=0;i<8;++i){ float v = p[i]; u16 h2 = f2bf(v); hh.s[i]=h2; ll.s[i]=f2bf(v - bf2f(h2)); }
    *(uint4*)(xh+u) = hh.v; *(uint4*)(xl+u) = ll.v;
  } else if (blk < 2144) {                // W: 3 * 32 blocks (Wq pre-scaled by 1/16)
    int q = blk - 2048; int mat = q >> 5;
    size_t off = (size_t)(q & 31)*2048 + (size_t)tid*8;
    const float* W = mat==0 ? Wq : (mat==1 ? Wk : Wv);
    float sc = (mat==0) ? 0.0625f : 1.0f;
    const float* p = W + off;
    union { u16 s[8]; uint4 v; } hh, ll;
    #pragma unroll
    for (int i=0;i<8;++i){ float v = p[i]*sc; u16 h2 = f2bf(v); hh.s[i]=h2; ll.s[i]=f2bf(v - bf2f(h2)); }
    size_t o = (size_t)mat*65536 + off;
    *(uint4*)(Wh+o) = hh.v; *(uint4*)(Wl+o) = ll.v;
  } else {                                // bias-ext cols: 64 blocks * 256 rows
    int row = (blk - 2144)*256 + tid;     // 0..16383 (b*4096+s)
    int s = row & (S-1);
    float b0 = beta[0], b1 = beta[1];
    int i24 = s % 24, i720 = s % 720;
    float t0 = (float)i24  * 0.26179938779914944f;    // 2pi/24
    float t1 = (float)i720 * 0.008726646259971648f;   // 2pi/720
    float c0 = cosf(t0), s0 = sinf(t0), c1 = cosf(t1), s1 = sinf(t1);
    float qv[4] = {b0*c0, b0*s0, b1*c1, b1*s1};   // beta folded on Q side
    float kv[4] = {c0, s0, c1, s1};
    u16* qp = Qb + (size_t)row*QSTR + 256;
    u16* kp = Kb + (size_t)row*QSTR + 256;
    #pragma unroll
    for (int n=0;n<4;++n){
      u16 uh = f2bf(qv[n]); u16 ul = f2bf(qv[n]-bf2f(uh));
      u16 vh = f2bf(kv[n]); u16 vl = f2bf(kv[n]-bf2f(vh));
      // dot over triplet = uh*vh + uh*vl + ul*vh ~= u*v  (drops ul*vl <= 2^-18)
      qp[n*3+0]=uh; qp[n*3+1]=uh; qp[n*3+2]=ul;
      kp[n*3+0]=vh; kp[n*3+1]=vl; kp[n*3+2]=vh;
    }
    #pragma unroll
    for (int c=12;c<16;++c){ qp[c]=0; kp[c]=0; }
  }
}

// ---------------- Q,K projection: [16384x256] = x @ W^T + b, bf16x3 split, 32x32x16 MFMA ----
__global__ __launch_bounds__(128,1) void msp_proj_qk(
    const u16* __restrict__ xh, const u16* __restrict__ xl,
    const u16* __restrict__ Wh, const u16* __restrict__ Wl,
    const float* __restrict__ bq, const float* __restrict__ bk,
    u16* __restrict__ Qb, u16* __restrict__ Kb)
{
  const int tid = threadIdx.x;
  const int wv = tid >> 6, lane = tid & 63;
  const int l31 = lane & 31, h = lane >> 5;
  const int m0 = blockIdx.x * 64;     // 256 blocks
  const int n0 = wv * 128;            // wave n-half
  #pragma unroll
  for (int mat = 0; mat < 2; ++mat) {
    const u16* wh = Wh + mat*65536;
    const u16* wl = Wl + mat*65536;
    f32x16 acc[2][4];
    #pragma unroll
    for (int a=0;a<2;++a)
      #pragma unroll
      for (int c=0;c<4;++c)
        #pragma unroll
        for (int i=0;i<16;++i) acc[a][c][i] = 0.f;
    #pragma unroll 4
    for (int k = 0; k < 16; ++k) {
      const int kc = k*16 + h*8;
      bf16x8 Ah[2], Al[2];
      #pragma unroll
      for (int mt=0; mt<2; ++mt) {
        size_t ra = (size_t)(m0 + mt*32 + l31)*D + kc;
        Ah[mt] = *(const bf16x8*)(xh + ra);
        Al[mt] = *(const bf16x8*)(xl + ra);
      }
      #pragma unroll
      for (int nt=0; nt<4; ++nt) {
        size_t rb = (size_t)(n0 + nt*32 + l31)*D + kc;
        bf16x8 Bh = *(const bf16x8*)(wh + rb);
        bf16x8 Bl = *(const bf16x8*)(wl + rb);
        #pragma unroll
        for (int mt=0; mt<2; ++mt) {
          acc[mt][nt] = __builtin_amdgcn_mfma_f32_32x32x16_bf16(Ah[mt], Bh, acc[mt][nt], 0,0,0);
          acc[mt][nt] = __builtin_amdgcn_mfma_f32_32x32x16_bf16(Ah[mt], Bl, acc[mt][nt], 0,0,0);
          acc[mt][nt] = __builtin_amdgcn_mfma_f32_32x32x16_bf16(Al[mt], Bh, acc[mt][nt], 0,0,0);
        }
      }
    }
    const float* bias = mat ? bk : bq;
    const float bsc = mat ? 1.0f : 0.0625f;   // W was pre-scaled; bias scaled here
    u16* outp = mat ? Kb : Qb;
    #pragma unroll
    for (int nt=0; nt<4; ++nt) {
      float bb = bias[n0 + nt*32 + l31] * bsc;
      #pragma unroll
      for (int mt=0; mt<2; ++mt)
        #pragma unroll
        for (int r=0; r<16; ++r) {
          int row = m0 + mt*32 + (r&3) + 8*(r>>2) + 4*h;
          outp[(size_t)row*QSTR + n0 + nt*32 + l31] = f2bf(acc[mt][nt][r] + bb);
        }
    }
  }
}

// ---------------- V^T projection: Vt[b][e][s] = (x Wv^T + bv)^T, transposed-orientation GEMM --
__global__ __launch_bounds__(128,1) void msp_proj_v(
    const u16* __restrict__ xh, const u16* __restrict__ xl,
    const u16* __restrict__ Wh, const u16* __restrict__ Wl,
    const float* __restrict__ bv, u16* __restrict__ Vt)
{
  const int tid = threadIdx.x;
  const int wv = tid >> 6, lane = tid & 63;
  const int l31 = lane & 31, h = lane >> 5;
  const int n0 = blockIdx.x*64 + wv*32;       // s index, 256 blocks
  const int b = n0 >> 12, sl = n0 & (S-1);
  const u16* wh = Wh + 2*65536;
  const u16* wl = Wl + 2*65536;
  f32x16 acc[8];
  #pragma unroll
  for (int e=0;e<8;++e)
    #pragma unroll
    for (int i=0;i<16;++i) acc[e][i] = 0.f;
  #pragma unroll 2
  for (int k=0;k<16;++k){
    const int kc = k*16 + h*8;
    size_t rb = (size_t)(n0 + l31)*D + kc;
    bf16x8 Bh = *(const bf16x8*)(xh + rb);
    bf16x8 Bl = *(const bf16x8*)(xl + rb);
    #pragma unroll
    for (int mt=0;mt<8;++mt){
      size_t ra = (size_t)(mt*32 + l31)*D + kc;
      bf16x8 Ah = *(const bf16x8*)(wh + ra);
      bf16x8 Al = *(const bf16x8*)(wl + ra);
      acc[mt] = __builtin_amdgcn_mfma_f32_32x32x16_bf16(Ah, Bh, acc[mt], 0,0,0);
      acc[mt] = __builtin_amdgcn_mfma_f32_32x32x16_bf16(Ah, Bl, acc[mt], 0,0,0);
      acc[mt] = __builtin_amdgcn_mfma_f32_32x32x16_bf16(Al, Bh, acc[mt], 0,0,0);
    }
  }
  #pragma unroll
  for (int mt=0;mt<8;++mt)
    #pragma unroll
    for (int r=0;r<16;++r){
      int e = mt*32 + (r&3) + 8*(r>>2) + 4*h;
      Vt[((size_t)(b*256 + e))*S + sl + l31] = f2bf(acc[mt][r] + bv[e]);
    }
}

// ---------------- flash attention, 32x32x16, bias via ext columns, double-buffered ----------
__global__ __launch_bounds__(128,1) void msp_attn(
    const u16* __restrict__ Qb, const u16* __restrict__ Kb,
    const u16* __restrict__ Vt, float* __restrict__ out)
{
  __shared__ u16 KtL[2][64][320];   // 81920 B: 64 keys x 272 (34 chunks, swizzled into 40)
  __shared__ u16 VsL[2][256][64];   // 65536 B: V^T tile, swizzled
  __shared__ u16 PtL[2][32][64];    //  8192 B: per-wave P, swizzled

  const int tid = threadIdx.x;
  const int wv = tid >> 6, lane = tid & 63;
  const int l31 = lane & 31, h = lane >> 5;
  const int b = blockIdx.y;
  const int qw = blockIdx.x * 64 + wv*32;

  bf16x8 qf[17];
  {
    const u16* qp = Qb + (size_t)(b*S + qw + l31)*QSTR + h*8;
    #pragma unroll
    for (int kf=0; kf<17; ++kf) qf[kf] = *(const bf16x8*)(qp + kf*16);
  }

  const u16* kgb = Kb + (size_t)(b*S)*QSTR;
  const u16* vgb = Vt + (size_t)(b*D)*S;

  const int krow = tid >> 1;           // K staging: 2 threads/row, 17 chunks each
  const int kcb  = (tid & 1) * 17;
  const int vrow0 = tid >> 3;          // V staging: 8 chunks/row, 16 row-passes
  const int vchk  = tid & 7;

  { // prologue: stage tile 0 into buffer 0
    const u16* kg = kgb + (size_t)krow*QSTR;
    #pragma unroll
    for (int i=0;i<17;++i){
      int c = kcb + i;
      uint4 d2 = *(const uint4*)(kg + c*8);
      *(uint4*)&KtL[0][krow][swz8(c, krow)*8] = d2;
    }
    #pragma unroll
    for (int q=0;q<16;++q){
      int row = q*16 + vrow0;
      uint4 d2 = *(const uint4*)(vgb + (size_t)row*S + vchk*8);
      *(uint4*)&VsL[0][row][((vchk ^ row)&7)*8] = d2;
    }
  }

  float m_run[16], l_run[16];
  #pragma unroll
  for (int r=0;r<16;++r){ m_run[r] = -3.0e38f; l_run[r] = 0.f; }
  f32x16 oacc[8];
  #pragma unroll
  for (int e=0;e<8;++e)
    #pragma unroll
    for (int i=0;i<16;++i) oacc[e][i] = 0.f;

  __syncthreads();

  for (int it = 0; it < 64; ++it) {
    const int p = it & 1;
    const int t0n = (it+1)*64;

    uint4 kreg[17]; uint4 vreg[16];
    if (it < 63) {   // issue next-tile global loads early
      const u16* kg = kgb + (size_t)(t0n + krow)*QSTR;
      #pragma unroll
      for (int i=0;i<17;++i) kreg[i] = *(const uint4*)(kg + (kcb+i)*8);
      #pragma unroll
      for (int q=0;q<16;++q){
        int row = q*16 + vrow0;
        vreg[q] = *(const uint4*)(vgb + (size_t)row*S + t0n + vchk*8);
      }
    }

    // S = Q' K'^T (scale + bias folded into the 272-dim)
    f32x16 sc[2];
    #pragma unroll
    for (int nt=0;nt<2;++nt)
      #pragma unroll
      for (int i=0;i<16;++i) sc[nt][i] = 0.f;
    #pragma unroll
    for (int kf=0; kf<17; ++kf){
      #pragma unroll
      for (int nt=0; nt<2; ++nt){
        int row = nt*32 + l31;
        int q = 2*kf + h;
        bf16x8 bk8 = *(const bf16x8*)&KtL[p][row][swz8(q, row)*8];
        sc[nt] = __builtin_amdgcn_mfma_f32_32x32x16_bf16(qf[kf], bk8, sc[nt], 0,0,0);
      }
    }

    // online softmax (stats per C-row, reduce over lane&31)
    float tmax[16];
    #pragma unroll
    for (int r=0;r<16;++r) tmax[r] = fmaxf(sc[0][r], sc[1][r]);
    #pragma unroll
    for (int off=1; off<32; off<<=1)
      #pragma unroll
      for (int r=0;r<16;++r) tmax[r] = fmaxf(tmax[r], __shfl_xor(tmax[r], off, 64));
    float alpha[16];
    #pragma unroll
    for (int r=0;r<16;++r){
      float mn = fmaxf(m_run[r], tmax[r]);
      alpha[r] = __expf(m_run[r] - mn);
      m_run[r] = mn;
    }
    float ps[16];
    #pragma unroll
    for (int r=0;r<16;++r) ps[r] = 0.f;
    #pragma unroll
    for (int nt=0; nt<2; ++nt)
      #pragma unroll
      for (int r=0;r<16;++r){
        float pv_ = __expf(sc[nt][r] - m_run[r]);
        u16 hp = f2bf(pv_);
        int row = (r&3) + 8*(r>>2) + 4*h;
        int col = nt*32 + l31;
        PtL[wv][row][(((col>>3) ^ row)&7)*8 + (col&7)] = hp;  // wave-private
        ps[r] += bf2f(hp);   // sum the rounded p so normalization cancels rounding
      }
    #pragma unroll
    for (int off=1; off<32; off<<=1)
      #pragma unroll
      for (int r=0;r<16;++r) ps[r] += __shfl_xor(ps[r], off, 64);
    #pragma unroll
    for (int r=0;r<16;++r) l_run[r] = l_run[r]*alpha[r] + ps[r];
    #pragma unroll
    for (int e=0;e<8;++e)
      #pragma unroll
      for (int r=0;r<16;++r) oacc[e][r] *= alpha[r];

    // O += P V
    bf16x8 af[4];
    #pragma unroll
    for (int kf=0;kf<4;++kf){
      int q = 2*kf + h;
      af[kf] = *(const bf16x8*)&PtL[wv][l31][((q ^ l31)&7)*8];
    }
    #pragma unroll
    for (int et=0; et<8; ++et){
      int row = et*32 + l31;
      #pragma unroll
      for (int kf=0;kf<4;++kf){
        int q = 2*kf + h;
        bf16x8 bv8 = *(const bf16x8*)&VsL[p][row][((q ^ row)&7)*8];
        oacc[et] = __builtin_amdgcn_mfma_f32_32x32x16_bf16(af[kf], bv8, oacc[et], 0,0,0);
      }
    }

    if (it < 63) {   // commit next tile to the other buffer
      #pragma unroll
      for (int i=0;i<17;++i)
        *(uint4*)&KtL[p^1][krow][swz8(kcb+i, krow)*8] = kreg[i];
      #pragma unroll
      for (int q=0;q<16;++q){
        int row = q*16 + vrow0;
        *(uint4*)&VsL[p^1][row][((vchk ^ row)&7)*8] = vreg[q];
      }
    }
    __syncthreads();   // single barrier per iteration
  }

  float inv[16];
  #pragma unroll
  for (int r=0;r<16;++r) inv[r] = 1.0f / l_run[r];
  float* ob = out + (size_t)(b*S + qw)*D;
  #pragma unroll
  for (int et=0; et<8; ++et)
    #pragma unroll
    for (int r=0;r<16;++r){
      int row = (r&3) + 8*(r>>2) + 4*h;
      ob[(size_t)row*D + et*32 + l31] = oacc[et][r]*inv[r];
    }
}

extern "C" void kernel_launch(void* const* d_in, const int* in_sizes, int n_in,
                              void* d_out, int out_size, void* d_ws, size_t ws_size,
                              hipStream_t stream) {
  const float* x    = (const float*)d_in[0];
  const float* Wq   = (const float*)d_in[1];
  const float* bq   = (const float*)d_in[2];
  const float* Wk   = (const float*)d_in[3];
  const float* bk   = (const float*)d_in[4];
  const float* Wv   = (const float*)d_in[5];
  const float* bv   = (const float*)d_in[6];
  const float* beta = (const float*)d_in[7];
  float* out = (float*)d_out;

  char* w = (char*)d_ws;
  u16* xh = (u16*)w;  w += (size_t)16384*256*2;
  u16* xl = (u16*)w;  w += (size_t)16384*256*2;
  u16* Qb = (u16*)w;  w += (size_t)16384*QSTR*2;
  u16* Kb = (u16*)w;  w += (size_t)16384*QSTR*2;
  u16* Vt = (u16*)w;  w += (size_t)16384*256*2;
  u16* Wh = (u16*)w;  w += (size_t)3*65536*2;
  u16* Wl = (u16*)w;  // total ~41.8 MB

  msp_prep<<<2208, 256, 0, stream>>>(x, Wq, Wk, Wv, beta, xh, xl, Wh, Wl, Qb, Kb);
  msp_proj_qk<<<256, 128, 0, stream>>>(xh, xl, Wh, Wl, bq, bk, Qb, Kb);
  msp_proj_v<<<256, 128, 0, stream>>>(xh, xl, Wh, Wl, bv, Vt);
  msp_attn<<<dim3(64, NB), 128, 0, stream>>>(Qb, Kb, Vt, out);
}

// Round 3
// 395.649 us; speedup vs baseline: 3.4792x; 3.4792x over previous
//
#include <hip/hip_runtime.h>
#include <math.h>
#include <stdint.h>

#define DEV static __device__ __forceinline__
typedef unsigned short u16;

constexpr int D    = 256;
constexpr int S    = 4096;
constexpr int NB   = 4;
constexpr int QSTR = 272;   // Qb/Kb row stride: 256 data + 12 bias-ext + 4 zero

typedef short bf16x8 __attribute__((ext_vector_type(8)));
typedef float f32x16 __attribute__((ext_vector_type(16)));

DEV u16 f2bf(float f){ unsigned u = __float_as_uint(f); return (u16)((u + 0x7fffu + ((u>>16)&1u)) >> 16); }
DEV float bf2f(u16 h){ return __uint_as_float(((unsigned)h)<<16); }
DEV int packbf(float lo, float hi){ return (int)((((unsigned)f2bf(hi)) << 16) | (unsigned)f2bf(lo)); }
DEV float bfsum2(int d){
  return __uint_as_float(((unsigned)d)<<16) + __uint_as_float(((unsigned)d) & 0xffff0000u);
}

// ---------------- prep: split x and W into bf16 hi/lo; write bias-ext columns ----------------
__global__ __launch_bounds__(256) void msp_prep(
    const float* __restrict__ x, const float* __restrict__ Wq,
    const float* __restrict__ Wk, const float* __restrict__ Wv,
    const float* __restrict__ beta,
    u16* __restrict__ xh, u16* __restrict__ xl,
    u16* __restrict__ Wh, u16* __restrict__ Wl,
    u16* __restrict__ Qb, u16* __restrict__ Kb)
{
  const int blk = blockIdx.x, tid = threadIdx.x;
  if (blk < 2048) {                       // x: 4x4096x256 = 2048 blocks * 2048 elts
    size_t u = (size_t)blk*2048 + tid*8;
    const float* p = x + u;
    union { u16 s[8]; uint4 v; } hh, ll;
    #pragma unroll
    for (int i=0;i<8;++i){ float v = p[i]; u16 h2 = f2bf(v); hh.s[i]=h2; ll.s[i]=f2bf(v - bf2f(h2)); }
    *(uint4*)(xh+u) = hh.v; *(uint4*)(xl+u) = ll.v;
  } else if (blk < 2144) {                // W: 3 * 32 blocks (Wq pre-scaled by 1/16)
    int q = blk - 2048; int mat = q >> 5;
    size_t off = (size_t)(q & 31)*2048 + (size_t)tid*8;
    const float* W = mat==0 ? Wq : (mat==1 ? Wk : Wv);
    float sc = (mat==0) ? 0.0625f : 1.0f;
    const float* p = W + off;
    union { u16 s[8]; uint4 v; } hh, ll;
    #pragma unroll
    for (int i=0;i<8;++i){ float v = p[i]*sc; u16 h2 = f2bf(v); hh.s[i]=h2; ll.s[i]=f2bf(v - bf2f(h2)); }
    size_t o = (size_t)mat*65536 + off;
    *(uint4*)(Wh+o) = hh.v; *(uint4*)(Wl+o) = ll.v;
  } else {                                // bias-ext cols: 64 blocks * 256 rows
    int row = (blk - 2144)*256 + tid;     // 0..16383 (b*4096+s)
    int s = row & (S-1);
    float b0 = beta[0], b1 = beta[1];
    int i24 = s % 24, i720 = s % 720;
    float t0 = (float)i24  * 0.26179938779914944f;    // 2pi/24
    float t1 = (float)i720 * 0.008726646259971648f;   // 2pi/720
    float c0 = cosf(t0), s0 = sinf(t0), c1 = cosf(t1), s1 = sinf(t1);
    float qv[4] = {b0*c0, b0*s0, b1*c1, b1*s1};   // beta folded on Q side
    float kv[4] = {c0, s0, c1, s1};
    u16* qp = Qb + (size_t)row*QSTR + 256;
    u16* kp = Kb + (size_t)row*QSTR + 256;
    #pragma unroll
    for (int n=0;n<4;++n){
      u16 uh = f2bf(qv[n]); u16 ul = f2bf(qv[n]-bf2f(uh));
      u16 vh = f2bf(kv[n]); u16 vl = f2bf(kv[n]-bf2f(vh));
      // dot over triplet = uh*vh + uh*vl + ul*vh ~= u*v  (drops ul*vl <= 2^-18)
      qp[n*3+0]=uh; qp[n*3+1]=uh; qp[n*3+2]=ul;
      kp[n*3+0]=vh; kp[n*3+1]=vl; kp[n*3+2]=vh;
    }
    #pragma unroll
    for (int c=12;c<16;++c){ qp[c]=0; kp[c]=0; }
  }
}

// ---------------- Q,K projection: 512 blocks x 128 thr, 32 rows/block ----------------
__global__ __launch_bounds__(128, 2) void msp_proj_qk(
    const u16* __restrict__ xh, const u16* __restrict__ xl,
    const u16* __restrict__ Wh, const u16* __restrict__ Wl,
    const float* __restrict__ bq, const float* __restrict__ bk,
    u16* __restrict__ Qb, u16* __restrict__ Kb)
{
  const int tid = threadIdx.x;
  const int wv = tid >> 6, lane = tid & 63;
  const int l31 = lane & 31, h = lane >> 5;
  const int m0 = blockIdx.x * 32;     // 512 blocks over 16384 rows
  const int n0 = wv * 128;            // wave n-half
  #pragma unroll
  for (int mat = 0; mat < 2; ++mat) {
    const u16* wh = Wh + mat*65536;
    const u16* wl = Wl + mat*65536;
    f32x16 acc[4];
    #pragma unroll
    for (int c=0;c<4;++c)
      #pragma unroll
      for (int i=0;i<16;++i) acc[c][i] = 0.f;
    #pragma unroll 4
    for (int k = 0; k < 16; ++k) {
      const int kc = k*16 + h*8;
      size_t ra = (size_t)(m0 + l31)*D + kc;
      bf16x8 Ah = *(const bf16x8*)(xh + ra);
      bf16x8 Al = *(const bf16x8*)(xl + ra);
      #pragma unroll
      for (int nt=0; nt<4; ++nt) {
        size_t rb = (size_t)(n0 + nt*32 + l31)*D + kc;
        bf16x8 Bh = *(const bf16x8*)(wh + rb);
        bf16x8 Bl = *(const bf16x8*)(wl + rb);
        acc[nt] = __builtin_amdgcn_mfma_f32_32x32x16_bf16(Ah, Bh, acc[nt], 0,0,0);
        acc[nt] = __builtin_amdgcn_mfma_f32_32x32x16_bf16(Ah, Bl, acc[nt], 0,0,0);
        acc[nt] = __builtin_amdgcn_mfma_f32_32x32x16_bf16(Al, Bh, acc[nt], 0,0,0);
      }
    }
    const float* bias = mat ? bk : bq;
    const float bsc = mat ? 1.0f : 0.0625f;   // W was pre-scaled; bias scaled here
    u16* outp = mat ? Kb : Qb;
    #pragma unroll
    for (int nt=0; nt<4; ++nt) {
      float bb = bias[n0 + nt*32 + l31] * bsc;
      #pragma unroll
      for (int r=0; r<16; ++r) {
        int row = m0 + (r&3) + 8*(r>>2) + 4*h;
        outp[(size_t)row*QSTR + n0 + nt*32 + l31] = f2bf(acc[nt][r] + bb);
      }
    }
  }
}

// ---------------- V^T projection: 512 blocks x 128 thr, 32 s-cols/block ----------------
__global__ __launch_bounds__(128, 2) void msp_proj_v(
    const u16* __restrict__ xh, const u16* __restrict__ xl,
    const u16* __restrict__ Wh, const u16* __restrict__ Wl,
    const float* __restrict__ bv, u16* __restrict__ Vt)
{
  const int tid = threadIdx.x;
  const int wv = tid >> 6, lane = tid & 63;
  const int l31 = lane & 31, h = lane >> 5;
  const int s0g = blockIdx.x * 32;           // global s-row over 16384
  const int b = s0g >> 12, sl = s0g & (S-1);
  const int e0 = wv * 128;                   // wave e-half
  const u16* wh = Wh + 2*65536;
  const u16* wl = Wl + 2*65536;
  f32x16 acc[4];
  #pragma unroll
  for (int c=0;c<4;++c)
    #pragma unroll
    for (int i=0;i<16;++i) acc[c][i] = 0.f;
  #pragma unroll 4
  for (int k=0;k<16;++k){
    const int kc = k*16 + h*8;
    size_t rb = (size_t)(s0g + l31)*D + kc;
    bf16x8 Bh = *(const bf16x8*)(xh + rb);
    bf16x8 Bl = *(const bf16x8*)(xl + rb);
    #pragma unroll
    for (int mt=0;mt<4;++mt){
      size_t ra = (size_t)(e0 + mt*32 + l31)*D + kc;
      bf16x8 Ah = *(const bf16x8*)(wh + ra);
      bf16x8 Al = *(const bf16x8*)(wl + ra);
      acc[mt] = __builtin_amdgcn_mfma_f32_32x32x16_bf16(Ah, Bh, acc[mt], 0,0,0);
      acc[mt] = __builtin_amdgcn_mfma_f32_32x32x16_bf16(Ah, Bl, acc[mt], 0,0,0);
      acc[mt] = __builtin_amdgcn_mfma_f32_32x32x16_bf16(Al, Bh, acc[mt], 0,0,0);
    }
  }
  #pragma unroll
  for (int mt=0;mt<4;++mt)
    #pragma unroll
    for (int r=0;r<16;++r){
      int e = e0 + mt*32 + (r&3) + 8*(r>>2) + 4*h;
      Vt[((size_t)(b*256 + e))*S + sl + l31] = f2bf(acc[mt][r] + bv[e]);
    }
}

// ---------------- attention: S^T = K Q^T, fixed-shift softmax, O^T = V^T P^T ----------------
// 512 thr = 8 waves: wave w -> qi = w&1 (q-tile of 32), tq = w>>1 (t-quarter of 1024).
// LDS: K [4][32][280] (stride16=35, odd -> conflict-free) + V^T [4][256][40] (stride16=5).
__global__ __launch_bounds__(512, 2) void msp_attn(
    const u16* __restrict__ Qb, const u16* __restrict__ Kb,
    const u16* __restrict__ Vt, float* __restrict__ out)
{
  __shared__ __align__(16) unsigned char smem[153600];
  u16* Ktb = (u16*)smem;                    // [4][32][280] = 71680 B
  u16* Vsb = (u16*)(smem + 71680);          // [4][256][40] = 81920 B

  const int tid = threadIdx.x;
  const int w = tid >> 6, lane = tid & 63;
  const int l31 = lane & 31, h = lane >> 5;
  const int qi = w & 1, tq = w >> 1;
  const int b = blockIdx.y;
  const int qv = blockIdx.x * 64 + qi * 32;

  // Q fragments (B-operand): lane holds Q[qv+l31][16s+8h+j]
  bf16x8 qf[17];
  {
    const u16* qp = Qb + ((size_t)(b*S) + qv + l31) * QSTR + h*8;
    #pragma unroll
    for (int s2=0; s2<17; ++s2) qf[s2] = *(const bf16x8*)(qp + s2*16);
  }

  const u16* kgb = Kb + (size_t)(b*S)*QSTR;
  const u16* vgb = Vt + (size_t)(b*D)*S;

  f32x16 oacc[8];
  #pragma unroll
  for (int e=0;e<8;++e)
    #pragma unroll
    for (int i=0;i<16;++i) oacc[e][i] = 0.f;
  float l_acc = 0.f;

  // staging roles: tile sg staged by thread group tid>>7
  const int sg   = tid >> 7;
  const int sl_  = tid & 127;
  const int krow = sl_ >> 2, kc0 = sl_ & 3;
  const int vrow = sl_;

  for (int it = 0; it < 32; ++it) {
    __syncthreads();   // previous iteration's LDS reads drained
    { // K tile sg: 32 rows x 34 chunks
      const u16* kg = kgb + (size_t)(sg*1024 + it*32 + krow) * QSTR;
      u16* kd = Ktb + (size_t)(sg*32 + krow) * 280;
      #pragma unroll
      for (int k2 = 0; k2 < 9; ++k2) {
        int c = kc0 + 4*k2;
        if (c < 34) *(uint4*)(kd + c*8) = *(const uint4*)(kg + c*8);
      }
      // V^T tile sg: 256 rows x 4 chunks
      #pragma unroll
      for (int p2 = 0; p2 < 2; ++p2) {
        int row = vrow + 128*p2;
        const u16* vg = vgb + (size_t)row * S + sg*1024 + it*32;
        u16* vd = Vsb + (size_t)(sg*256 + row) * 40;
        #pragma unroll
        for (int c = 0; c < 4; ++c)
          *(uint4*)(vd + c*8) = *(const uint4*)(vg + c*8);
      }
    }
    __syncthreads();

    // S^T = K Q^T  (scale + periodic bias folded into the 272-dim)
    f32x16 sc;
    #pragma unroll
    for (int i=0;i<16;++i) sc[i] = 0.f;
    {
      const u16* krd = Ktb + (size_t)(tq*32 + l31) * 280 + h*8;
      #pragma unroll
      for (int s2 = 0; s2 < 17; ++s2) {
        bf16x8 kf = *(const bf16x8*)(krd + s2*16);
        sc = __builtin_amdgcn_mfma_f32_32x32x16_bf16(kf, qf[s2], sc, 0,0,0);
      }
    }

    // p = exp(s) (fixed shift 0: scores bounded ~|9|), pack P^T B-frags via xor-32 exchange
    bf16x8 pf[2];
    #pragma unroll
    for (int s2 = 0; s2 < 2; ++s2) {
      float e0 = __expf(sc[8*s2+0]), e1 = __expf(sc[8*s2+1]);
      float e2 = __expf(sc[8*s2+2]), e3 = __expf(sc[8*s2+3]);
      float e4 = __expf(sc[8*s2+4]), e5 = __expf(sc[8*s2+5]);
      float e6 = __expf(sc[8*s2+6]), e7 = __expf(sc[8*s2+7]);
      int P0d0 = packbf(e0, e1), P0d1 = packbf(e2, e3);
      int P1d0 = packbf(e4, e5), P1d1 = packbf(e6, e7);
      // l sums the bf16-ROUNDED p so normalization cancels rounding bias
      l_acc += bfsum2(P0d0) + bfsum2(P0d1) + bfsum2(P1d0) + bfsum2(P1d1);
      int s0 = h ? P0d0 : P1d0;
      int s1 = h ? P0d1 : P1d1;
      int r0 = __shfl_xor(s0, 32, 64);
      int r1 = __shfl_xor(s1, 32, 64);
      union { int d[4]; bf16x8 v; } u;
      u.d[0] = h ? r0 : P0d0;
      u.d[1] = h ? r1 : P0d1;
      u.d[2] = h ? P1d0 : r0;
      u.d[3] = h ? P1d1 : r1;
      pf[s2] = u.v;
    }

    // O^T += V^T P^T
    #pragma unroll
    for (int et = 0; et < 8; ++et) {
      const u16* vb = Vsb + (size_t)(tq*256 + et*32 + l31) * 40 + h*8;
      oacc[et] = __builtin_amdgcn_mfma_f32_32x32x16_bf16(*(const bf16x8*)(vb),      pf[0], oacc[et], 0,0,0);
      oacc[et] = __builtin_amdgcn_mfma_f32_32x32x16_bf16(*(const bf16x8*)(vb + 16), pf[1], oacc[et], 0,0,0);
    }
  }

  // fold the two h-halves of l (each summed its own 16 keys/iter)
  float l_tot = l_acc + __shfl_xor(l_acc, 32, 64);

  // t-quarter merge via LDS (reuse tile space): Om[slot][lane][132] (stride16=33, odd)
  float* Om = (float*)smem;     // 4 slots x 64 x 132 floats = 135168 B
  __syncthreads();
  if (tq >= 2) {                // round A writers
    float* orow = Om + (size_t)((qi*2 + (tq-2))*64 + lane) * 132;
    #pragma unroll
    for (int et=0; et<8; ++et)
      #pragma unroll
      for (int r=0; r<16; ++r) orow[et*16+r] = oacc[et][r];
    orow[128] = l_tot;
  }
  __syncthreads();
  if (tq < 2) {                 // round A adders
    const float* orow = Om + (size_t)((qi*2 + tq)*64 + lane) * 132;
    #pragma unroll
    for (int et=0; et<8; ++et)
      #pragma unroll
      for (int r=0; r<16; ++r) oacc[et][r] += orow[et*16+r];
    l_tot += orow[128];
  }
  __syncthreads();
  if (tq == 1) {                // round B writer
    float* orow = Om + (size_t)((qi*2)*64 + lane) * 132;
    #pragma unroll
    for (int et=0; et<8; ++et)
      #pragma unroll
      for (int r=0; r<16; ++r) orow[et*16+r] = oacc[et][r];
    orow[128] = l_tot;
  }
  __syncthreads();
  if (tq == 0) {                // final merge + normalize + store
    const float* orow = Om + (size_t)((qi*2)*64 + lane) * 132;
    l_tot += orow[128];
    float inv = 1.0f / l_tot;
    float* ob = out + ((size_t)(b*S) + qv + l31) * D;
    #pragma unroll
    for (int et=0; et<8; ++et)
      #pragma unroll
      for (int r=0; r<16; ++r) {
        int e = et*32 + (r&3) + 8*(r>>2) + 4*h;
        ob[e] = (oacc[et][r] + orow[et*16+r]) * inv;
      }
  }
}

extern "C" void kernel_launch(void* const* d_in, const int* in_sizes, int n_in,
                              void* d_out, int out_size, void* d_ws, size_t ws_size,
                              hipStream_t stream) {
  const float* x    = (const float*)d_in[0];
  const float* Wq   = (const float*)d_in[1];
  const float* bq   = (const float*)d_in[2];
  const float* Wk   = (const float*)d_in[3];
  const float* bk   = (const float*)d_in[4];
  const float* Wv   = (const float*)d_in[5];
  const float* bv   = (const float*)d_in[6];
  const float* beta = (const float*)d_in[7];
  float* out = (float*)d_out;

  char* w = (char*)d_ws;
  u16* xh = (u16*)w;  w += (size_t)16384*256*2;
  u16* xl = (u16*)w;  w += (size_t)16384*256*2;
  u16* Qb = (u16*)w;  w += (size_t)16384*QSTR*2;
  u16* Kb = (u16*)w;  w += (size_t)16384*QSTR*2;
  u16* Vt = (u16*)w;  w += (size_t)16384*256*2;
  u16* Wh = (u16*)w;  w += (size_t)3*65536*2;
  u16* Wl = (u16*)w;  // total ~41.8 MB

  msp_prep<<<2208, 256, 0, stream>>>(x, Wq, Wk, Wv, beta, xh, xl, Wh, Wl, Qb, Kb);
  msp_proj_qk<<<512, 128, 0, stream>>>(xh, xl, Wh, Wl, bq, bk, Qb, Kb);
  msp_proj_v<<<512, 128, 0, stream>>>(xh, xl, Wh, Wl, bv, Vt);
  msp_attn<<<dim3(64, NB), 512, 0, stream>>>(Qb, Kb, Vt, out);
}

// Round 4
// 292.330 us; speedup vs baseline: 4.7089x; 1.3534x over previous
//
#include <hip/hip_runtime.h>
#include <math.h>
#include <stdint.h>

#define DEV static __device__ __forceinline__
typedef unsigned short u16;

constexpr int D    = 256;
constexpr int S    = 4096;
constexpr int QSTR = 272;   // Q row: 256 data + 12 bias-ext + 4 zero
constexpr int KROW = 280;   // K tile row stride (u16): 272 data + 8 pad, odd*16B
constexpr int VROW = 72;    // V tile row stride (u16): 64 keys + 8 pad, odd*16B

typedef short bf16x8 __attribute__((ext_vector_type(8)));
typedef float f32x16 __attribute__((ext_vector_type(16)));

DEV u16 f2bf(float f){ unsigned u = __float_as_uint(f); return (u16)((u + 0x7fffu + ((u>>16)&1u)) >> 16); }
DEV float bf2f(u16 h){ return __uint_as_float(((unsigned)h)<<16); }
DEV int packbf(float lo, float hi){ return (int)((((unsigned)f2bf(hi)) << 16) | (unsigned)f2bf(lo)); }
DEV float bfsum2(int d){
  return __uint_as_float(((unsigned)d)<<16) + __uint_as_float(((unsigned)d) & 0xffff0000u);
}

// async global->LDS, 16B per lane; LDS dest = wave-uniform base + lane*16
DEV void gl_lds16(const u16* g, u16* l) {
  __builtin_amdgcn_global_load_lds(
      (const __attribute__((address_space(1))) unsigned int*)g,
      (__attribute__((address_space(3))) unsigned int*)l, 16, 0, 0);
}

// ---------------- prep: hi/lo split of x,W; bias-ext columns; zero out/Lacc ----------------
__global__ __launch_bounds__(256) void msp_prep(
    const float* __restrict__ x, const float* __restrict__ Wq,
    const float* __restrict__ Wk, const float* __restrict__ Wv,
    const float* __restrict__ beta,
    u16* __restrict__ xh, u16* __restrict__ xl,
    u16* __restrict__ Wh, u16* __restrict__ Wl,
    u16* __restrict__ Qb, u16* __restrict__ Kt,
    float* __restrict__ out, float* __restrict__ Lacc)
{
  const int blk = blockIdx.x, tid = threadIdx.x;
  if (blk < 2048) {                       // x hi/lo
    size_t u = (size_t)blk*2048 + tid*8;
    const float* p = x + u;
    union { u16 s[8]; uint4 v; } hh, ll;
    #pragma unroll
    for (int i=0;i<8;++i){ float v = p[i]; u16 h2 = f2bf(v); hh.s[i]=h2; ll.s[i]=f2bf(v - bf2f(h2)); }
    *(uint4*)(xh+u) = hh.v; *(uint4*)(xl+u) = ll.v;
  } else if (blk < 2144) {                // W hi/lo (Wq pre-scaled by 1/16)
    int q = blk - 2048; int mat = q >> 5;
    size_t off = (size_t)(q & 31)*2048 + (size_t)tid*8;
    const float* W = mat==0 ? Wq : (mat==1 ? Wk : Wv);
    float sc = (mat==0) ? 0.0625f : 1.0f;
    const float* p = W + off;
    union { u16 s[8]; uint4 v; } hh, ll;
    #pragma unroll
    for (int i=0;i<8;++i){ float v = p[i]*sc; u16 h2 = f2bf(v); hh.s[i]=h2; ll.s[i]=f2bf(v - bf2f(h2)); }
    size_t o = (size_t)mat*65536 + off;
    *(uint4*)(Wh+o) = hh.v; *(uint4*)(Wl+o) = ll.v;
  } else if (blk < 2208) {                // bias-ext cols
    int row = (blk - 2144)*256 + tid;     // b*4096 + s
    int s = row & (S-1);
    int b = row >> 12;
    float b0 = beta[0], b1 = beta[1];
    int i24 = s % 24, i720 = s % 720;
    float t0 = (float)i24  * 0.26179938779914944f;    // 2pi/24
    float t1 = (float)i720 * 0.008726646259971648f;   // 2pi/720
    float c0 = cosf(t0), s0 = sinf(t0), c1 = cosf(t1), s1 = sinf(t1);
    float qv[4] = {b0*c0, b0*s0, b1*c1, b1*s1};   // beta folded on Q side
    float kv[4] = {c0, s0, c1, s1};
    u16* qp = Qb + (size_t)row*QSTR + 256;
    u16* kp = Kt + ((size_t)((b*64 + (s>>6))*64) + (s&63))*KROW + 256;
    #pragma unroll
    for (int n=0;n<4;++n){
      u16 uh = f2bf(qv[n]); u16 ul = f2bf(qv[n]-bf2f(uh));
      u16 vh = f2bf(kv[n]); u16 vl = f2bf(kv[n]-bf2f(vh));
      qp[n*3+0]=uh; qp[n*3+1]=uh; qp[n*3+2]=ul;
      kp[n*3+0]=vh; kp[n*3+1]=vl; kp[n*3+2]=vh;
    }
    #pragma unroll
    for (int c=12;c<16;++c){ qp[c]=0; kp[c]=0; }
  } else if (blk < 3232) {                // zero out (16.8 MB)
    float4* p = (float4*)(out + (size_t)(blk-2208)*4096);
    float4 z = {0.f,0.f,0.f,0.f};
    #pragma unroll
    for (int c=0;c<4;++c) p[tid + c*256] = z;
  } else {                                // zero Lacc
    float4* p = (float4*)(Lacc + (size_t)(blk-3232)*4096);
    float4 z = {0.f,0.f,0.f,0.f};
    #pragma unroll
    for (int c=0;c<4;++c) p[tid + c*256] = z;
  }
}

// ---------------- Q,K projection (K stored tiled) ----------------
__global__ __launch_bounds__(128, 2) void msp_proj_qk(
    const u16* __restrict__ xh, const u16* __restrict__ xl,
    const u16* __restrict__ Wh, const u16* __restrict__ Wl,
    const float* __restrict__ bq, const float* __restrict__ bk,
    u16* __restrict__ Qb, u16* __restrict__ Kt)
{
  const int tid = threadIdx.x;
  const int wv = tid >> 6, lane = tid & 63;
  const int l31 = lane & 31, h = lane >> 5;
  const int m0 = blockIdx.x * 32;
  const int n0 = wv * 128;
  #pragma unroll
  for (int mat = 0; mat < 2; ++mat) {
    const u16* wh = Wh + mat*65536;
    const u16* wl = Wl + mat*65536;
    f32x16 acc[4];
    #pragma unroll
    for (int c=0;c<4;++c)
      #pragma unroll
      for (int i=0;i<16;++i) acc[c][i] = 0.f;
    #pragma unroll 4
    for (int k = 0; k < 16; ++k) {
      const int kc = k*16 + h*8;
      size_t ra = (size_t)(m0 + l31)*D + kc;
      bf16x8 Ah = *(const bf16x8*)(xh + ra);
      bf16x8 Al = *(const bf16x8*)(xl + ra);
      #pragma unroll
      for (int nt=0; nt<4; ++nt) {
        size_t rb = (size_t)(n0 + nt*32 + l31)*D + kc;
        bf16x8 Bh = *(const bf16x8*)(wh + rb);
        bf16x8 Bl = *(const bf16x8*)(wl + rb);
        acc[nt] = __builtin_amdgcn_mfma_f32_32x32x16_bf16(Ah, Bh, acc[nt], 0,0,0);
        acc[nt] = __builtin_amdgcn_mfma_f32_32x32x16_bf16(Ah, Bl, acc[nt], 0,0,0);
        acc[nt] = __builtin_amdgcn_mfma_f32_32x32x16_bf16(Al, Bh, acc[nt], 0,0,0);
      }
    }
    const float* bias = mat ? bk : bq;
    const float bsc = mat ? 1.0f : 0.0625f;
    #pragma unroll
    for (int nt=0; nt<4; ++nt) {
      float bb = bias[n0 + nt*32 + l31] * bsc;
      #pragma unroll
      for (int r=0; r<16; ++r) {
        int row = m0 + (r&3) + 8*(r>>2) + 4*h;
        int col = n0 + nt*32 + l31;
        u16 val = f2bf(acc[nt][r] + bb);
        if (mat == 0) {
          Qb[(size_t)row*QSTR + col] = val;
        } else {
          int b = row >> 12, s = row & (S-1);
          Kt[((size_t)((b*64 + (s>>6))*64) + (s&63))*KROW + col] = val;
        }
      }
    }
  }
}

// ---------------- V^T projection, tiled [b][t64][256 e][72] ----------------
__global__ __launch_bounds__(128, 2) void msp_proj_v(
    const u16* __restrict__ xh, const u16* __restrict__ xl,
    const u16* __restrict__ Wh, const u16* __restrict__ Wl,
    const float* __restrict__ bv, u16* __restrict__ Vt)
{
  const int tid = threadIdx.x;
  const int wv = tid >> 6, lane = tid & 63;
  const int l31 = lane & 31, h = lane >> 5;
  const int s0g = blockIdx.x * 32;
  const int b = s0g >> 12, sl = s0g & (S-1);
  const int e0 = wv * 128;
  const u16* wh = Wh + 2*65536;
  const u16* wl = Wl + 2*65536;
  f32x16 acc[4];
  #pragma unroll
  for (int c=0;c<4;++c)
    #pragma unroll
    for (int i=0;i<16;++i) acc[c][i] = 0.f;
  #pragma unroll 4
  for (int k=0;k<16;++k){
    const int kc = k*16 + h*8;
    size_t rb = (size_t)(s0g + l31)*D + kc;
    bf16x8 Bh = *(const bf16x8*)(xh + rb);
    bf16x8 Bl = *(const bf16x8*)(xl + rb);
    #pragma unroll
    for (int mt=0;mt<4;++mt){
      size_t ra = (size_t)(e0 + mt*32 + l31)*D + kc;
      bf16x8 Ah = *(const bf16x8*)(wh + ra);
      bf16x8 Al = *(const bf16x8*)(wl + ra);
      acc[mt] = __builtin_amdgcn_mfma_f32_32x32x16_bf16(Ah, Bh, acc[mt], 0,0,0);
      acc[mt] = __builtin_amdgcn_mfma_f32_32x32x16_bf16(Ah, Bl, acc[mt], 0,0,0);
      acc[mt] = __builtin_amdgcn_mfma_f32_32x32x16_bf16(Al, Bh, acc[mt], 0,0,0);
    }
  }
  #pragma unroll
  for (int mt=0;mt<4;++mt)
    #pragma unroll
    for (int r=0;r<16;++r){
      int e = e0 + mt*32 + (r&3) + 8*(r>>2) + 4*h;
      int scol = sl + l31;
      Vt[((size_t)((b*64 + (scol>>6))*256) + e)*VROW + (scol&63)] = f2bf(acc[mt][r] + bv[e]);
    }
}

// ---------------- attention: async-LDS double-buffered, t-split partials via atomics ---------
__global__ __launch_bounds__(512, 1) void msp_attn(
    const u16* __restrict__ Qb, const u16* __restrict__ Kt,
    const u16* __restrict__ Vt, float* __restrict__ out,
    float* __restrict__ Lacc)
{
  __shared__ __align__(16) unsigned char smem[145408];  // 2 x (35840 K + 36864 V)
  u16* lds = (u16*)smem;

  const int tid = threadIdx.x;
  const int wv = tid >> 6, lane = tid & 63;
  const int l31 = lane & 31, h = lane >> 5;

  // XCD-swizzled decode (bijection over 256 blocks): blocks sharing (b,tq) land on one XCD
  const int xg = blockIdx.x;
  const int xcd = xg & 7, j = xg >> 3;
  const int c = xcd*2 + (j & 1);
  const int qt = j >> 1;
  const int b = c >> 2, tq = c & 3;
  const int q0 = qt * 256;

  // Q fragments (B-operand)
  bf16x8 qf[17];
  {
    const u16* qp = Qb + ((size_t)(b*S) + q0 + wv*32 + l31) * QSTR + h*8;
    #pragma unroll
    for (int s2=0; s2<17; ++s2) qf[s2] = *(const bf16x8*)(qp + s2*16);
  }

  const int tile0 = b*64 + tq*16;
  f32x16 oacc[8];
  #pragma unroll
  for (int e=0;e<8;++e)
    #pragma unroll
    for (int i=0;i<16;++i) oacc[e][i] = 0.f;
  float l_acc = 0.f;

  // prologue: stage tile 0 into buffer 0
  {
    const u16* kg = Kt + (size_t)(tile0*64) * KROW;
    const u16* vg = Vt + (size_t)(tile0*256) * VROW;
    #pragma unroll
    for (int ii=0; ii<5; ++ii){ int i = wv + ii*8; if (i < 35) gl_lds16(kg + i*512 + lane*8, lds + i*512); }
    #pragma unroll
    for (int ii=0; ii<5; ++ii){ int i = wv + ii*8; if (i < 36) gl_lds16(vg + i*512 + lane*8, lds + 17920 + i*512); }
  }

  for (int it = 0; it < 16; ++it) {
    __syncthreads();            // buf[it&1] staged; previous compute drained
    const int p = it & 1;
    if (it < 15) {              // async-stage next tile into other buffer
      const u16* kg = Kt + (size_t)((tile0 + it + 1)*64) * KROW;
      const u16* vg = Vt + (size_t)((tile0 + it + 1)*256) * VROW;
      u16* kl = lds + (p^1)*36352;
      u16* vl = kl + 17920;
      #pragma unroll
      for (int ii=0; ii<5; ++ii){ int i = wv + ii*8; if (i < 35) gl_lds16(kg + i*512 + lane*8, kl + i*512); }
      #pragma unroll
      for (int ii=0; ii<5; ++ii){ int i = wv + ii*8; if (i < 36) gl_lds16(vg + i*512 + lane*8, vl + i*512); }
    }
    const u16* Kl = lds + p*36352;
    const u16* Vl = Kl + 17920;

    // S^T = K Q^T  (scale + periodic bias folded into the 272-dim)
    f32x16 sc[2];
    #pragma unroll
    for (int nk=0;nk<2;++nk)
      #pragma unroll
      for (int i=0;i<16;++i) sc[nk][i] = 0.f;
    #pragma unroll
    for (int s2 = 0; s2 < 17; ++s2) {
      #pragma unroll
      for (int nk = 0; nk < 2; ++nk) {
        bf16x8 kf = *(const bf16x8*)&Kl[(size_t)(nk*32 + l31)*KROW + s2*16 + h*8];
        sc[nk] = __builtin_amdgcn_mfma_f32_32x32x16_bf16(kf, qf[s2], sc[nk], 0,0,0);
      }
    }

    // p = exp(s) (fixed shift; scores bounded), pack P^T B-frags via xor-32 exchange
    bf16x8 pf[4];
    #pragma unroll
    for (int nk = 0; nk < 2; ++nk) {
      #pragma unroll
      for (int s2 = 0; s2 < 2; ++s2) {
        float e0 = __expf(sc[nk][8*s2+0]), e1 = __expf(sc[nk][8*s2+1]);
        float e2 = __expf(sc[nk][8*s2+2]), e3 = __expf(sc[nk][8*s2+3]);
        float e4 = __expf(sc[nk][8*s2+4]), e5 = __expf(sc[nk][8*s2+5]);
        float e6 = __expf(sc[nk][8*s2+6]), e7 = __expf(sc[nk][8*s2+7]);
        int P0d0 = packbf(e0, e1), P0d1 = packbf(e2, e3);
        int P1d0 = packbf(e4, e5), P1d1 = packbf(e6, e7);
        l_acc += bfsum2(P0d0) + bfsum2(P0d1) + bfsum2(P1d0) + bfsum2(P1d1);
        int s0 = h ? P0d0 : P1d0;
        int s1 = h ? P0d1 : P1d1;
        int r0 = __shfl_xor(s0, 32, 64);
        int r1 = __shfl_xor(s1, 32, 64);
        union { int d[4]; bf16x8 v; } u;
        u.d[0] = h ? r0 : P0d0;
        u.d[1] = h ? r1 : P0d1;
        u.d[2] = h ? P1d0 : r0;
        u.d[3] = h ? P1d1 : r1;
        pf[nk*2 + s2] = u.v;
      }
    }

    // O^T += V^T P^T
    #pragma unroll
    for (int et = 0; et < 8; ++et) {
      const u16* vb = Vl + (size_t)(et*32 + l31)*VROW + h*8;
      #pragma unroll
      for (int kc = 0; kc < 4; ++kc)
        oacc[et] = __builtin_amdgcn_mfma_f32_32x32x16_bf16(*(const bf16x8*)(vb + kc*16), pf[kc], oacc[et], 0,0,0);
    }
  }

  // l: fold h-halves, one atomic per q-row
  float l_tot = l_acc + __shfl_xor(l_acc, 32, 64);
  if (h == 0) unsafeAtomicAdd(&Lacc[(size_t)(b*S) + q0 + wv*32 + l31], l_tot);

  // transpose O^T -> O via LDS (2 rounds), then coalesced fp32 atomics into out
  float* Ofl = (float*)smem;    // [128 q][260] per round
  __syncthreads();
  #pragma unroll
  for (int round = 0; round < 2; ++round) {
    if ((wv >> 2) == round) {
      int qrow = (wv & 3)*32 + l31;
      #pragma unroll
      for (int et=0; et<8; ++et)
        #pragma unroll
        for (int g=0; g<4; ++g) {
          float4 v4 = { oacc[et][4*g+0], oacc[et][4*g+1], oacc[et][4*g+2], oacc[et][4*g+3] };
          *(float4*)&Ofl[(size_t)qrow*260 + et*32 + 8*g + 4*h] = v4;
        }
    }
    __syncthreads();
    float* obase = out + (size_t)(b*S + q0 + round*128) * D;
    #pragma unroll
    for (int jj = 0; jj < 64; ++jj) {
      int flat = (jj*8 + wv)*64 + lane;
      int q = flat >> 8, e = flat & 255;
      unsafeAtomicAdd(obase + (size_t)q*D + e, Ofl[(size_t)q*260 + e]);
    }
    __syncthreads();
  }
}

// ---------------- normalize ----------------
__global__ __launch_bounds__(256) void msp_norm(float* __restrict__ out, const float* __restrict__ L) {
  int idx = blockIdx.x*256 + threadIdx.x;
  int row = idx >> 6, e0 = (idx & 63)*4;
  float inv = 1.0f / L[row];
  float4* p = (float4*)(out + (size_t)row*256 + e0);
  float4 v = *p;
  v.x *= inv; v.y *= inv; v.z *= inv; v.w *= inv;
  *p = v;
}

extern "C" void kernel_launch(void* const* d_in, const int* in_sizes, int n_in,
                              void* d_out, int out_size, void* d_ws, size_t ws_size,
                              hipStream_t stream) {
  const float* x    = (const float*)d_in[0];
  const float* Wq   = (const float*)d_in[1];
  const float* bq   = (const float*)d_in[2];
  const float* Wk   = (const float*)d_in[3];
  const float* bk   = (const float*)d_in[4];
  const float* Wv   = (const float*)d_in[5];
  const float* bv   = (const float*)d_in[6];
  const float* beta = (const float*)d_in[7];
  float* out = (float*)d_out;

  char* w = (char*)d_ws;
  u16* xh = (u16*)w;  w += (size_t)16384*256*2;
  u16* xl = (u16*)w;  w += (size_t)16384*256*2;
  u16* Qb = (u16*)w;  w += (size_t)16384*QSTR*2;
  u16* Kt = (u16*)w;  w += (size_t)256*64*KROW*2;   // [b*64+t64][64][280]
  u16* Vt = (u16*)w;  w += (size_t)256*256*VROW*2;  // [b*64+t64][256][72]
  u16* Wh = (u16*)w;  w += (size_t)3*65536*2;
  u16* Wl = (u16*)w;  w += (size_t)3*65536*2;
  float* Lacc = (float*)w;                           // 16384 f32

  msp_prep<<<3236, 256, 0, stream>>>(x, Wq, Wk, Wv, beta, xh, xl, Wh, Wl, Qb, Kt, out, Lacc);
  msp_proj_qk<<<512, 128, 0, stream>>>(xh, xl, Wh, Wl, bq, bk, Qb, Kt);
  msp_proj_v<<<512, 128, 0, stream>>>(xh, xl, Wh, Wl, bv, Vt);
  msp_attn<<<256, 512, 0, stream>>>(Qb, Kt, Vt, out, Lacc);
  msp_norm<<<4096, 256, 0, stream>>>(out, Lacc);
}